// Round 5
// baseline (78.893 us; speedup 1.0000x reference)
//
#include <hip/hip_runtime.h>

// B=256, N=25, C=256, H/2=128.
// Telescoping: edge_feat[b,i,j,:] = src[b,j]-src[b,i]  =>  u = src @ W1^T (bf16 MFMA).
// PReLU identity: max(d,0)=max(uj,ui)-ui =>
//   out[i,j] = (1-a)*M[i,j] + a*s_j - s_i,  M symmetric => 300 upper-tri pairs,
//   diagonal exactly 0.
//
// R5: single kernel, single barrier. A/B fragments gathered directly from
// global (R4 showed row-gathers cost ~1 us total, less than a kernel node +
// prep pass). LDS holds only u (13.2 KB). Grid 256 = 1 block (1 batch) / CU.
#define NJ   25
#define CIN  256
#define HH   128

typedef __attribute__((ext_vector_type(8))) short short8;
typedef __attribute__((ext_vector_type(4))) float f32x4;

__device__ __forceinline__ unsigned short f2bf(float f) {
    union { float f; unsigned u; } v; v.f = f;
    unsigned r = v.u + 0x7FFF + ((v.u >> 16) & 1);   // RNE
    return (unsigned short)(r >> 16);
}
__device__ __forceinline__ short8 mkfrag(float4 x, float4 y) {
    short8 o;
    o[0] = (short)f2bf(x.x); o[1] = (short)f2bf(x.y);
    o[2] = (short)f2bf(x.z); o[3] = (short)f2bf(x.w);
    o[4] = (short)f2bf(y.x); o[5] = (short)f2bf(y.y);
    o[6] = (short)f2bf(y.z); o[7] = (short)f2bf(y.w);
    return o;
}

__global__ __launch_bounds__(512) void fused_edge_mlp_v5(
    const float* __restrict__ src,   // [B,25,256]
    const float* __restrict__ W1,    // [128,256]
    const float* __restrict__ Aarr,  // [1] alpha
    const float* __restrict__ W2,    // [128]
    float* __restrict__ out)         // [B,25,25]
{
    __shared__ float u_s[NJ * 132];  // u fp32, row stride 132 (13.2 KB)

    const int b    = blockIdx.x;
    const int t    = threadIdx.x;
    const int w    = t >> 6;         // wave = h N-tile (16 cols)
    const int lane = t & 63;
    const int ln15 = lane & 15;
    const int quad = lane >> 4;
    const int hcol = w * 16 + ln15;

    // ---- Phase 1: u = src_bf16 @ W1_bf16^T, frags gathered straight from global
    {
        const float* w1p  = W1 + (size_t)hcol * CIN + quad * 8;          // B row
        const float* sp0  = src + ((size_t)b * NJ + ln15) * CIN + quad * 8;       // A rows 0..15
        const float* sp1  = sp0 + 16 * CIN;                               // A rows 16..31
        const bool   r1ok = (ln15 < NJ - 16);                             // rows 16..24 valid

        f32x4 acc0 = {0.f, 0.f, 0.f, 0.f};
        f32x4 acc1 = {0.f, 0.f, 0.f, 0.f};
        #pragma unroll
        for (int kt = 0; kt < 8; ++kt) {
            const int ko = kt * 32;
            float4 bx = *(const float4*)(w1p + ko);
            float4 by = *(const float4*)(w1p + ko + 4);
            float4 a0x = *(const float4*)(sp0 + ko);
            float4 a0y = *(const float4*)(sp0 + ko + 4);
            float4 zz = {0.f, 0.f, 0.f, 0.f};
            float4 a1x = zz, a1y = zz;
            if (r1ok) { a1x = *(const float4*)(sp1 + ko); a1y = *(const float4*)(sp1 + ko + 4); }
            short8 bf = mkfrag(bx, by);
            acc0 = __builtin_amdgcn_mfma_f32_16x16x32_bf16(mkfrag(a0x, a0y), bf, acc0, 0, 0, 0);
            acc1 = __builtin_amdgcn_mfma_f32_16x16x32_bf16(mkfrag(a1x, a1y), bf, acc1, 0, 0, 0);
        }

        // D layout: col(h)=lane&15, row(m)=quad*4+reg
        #pragma unroll
        for (int r = 0; r < 4; ++r) {
            int m0 = quad * 4 + r;
            if (m0 < NJ) u_s[m0 * 132 + hcol] = acc0[r];
            int m1 = 16 + quad * 4 + r;
            if (m1 < NJ) u_s[m1 * 132 + hcol] = acc1[r];
        }
    }
    __syncthreads();

    // ---- Phase 2: 300 upper-tri pairs + 25 diagonal zeros ----
    const float alpha = Aarr[0];
    float* outb = out + (size_t)b * (NJ * NJ);

    if (t < 300) {
        int i = (int)((49.0f - sqrtf(2401.0f - 8.0f * (float)t)) * 0.5f);
        {   // fp-safety clamp
            int Si = (49 * i - i * i) >> 1;
            if (t < Si) { --i; }
            else { int Sn = (49 * (i + 1) - (i + 1) * (i + 1)) >> 1; if (t >= Sn) ++i; }
        }
        const int S = (49 * i - i * i) >> 1;
        const int j = t - S + i + 1;

        const float* uj = u_s + j * 132;
        const float* ui = u_s + i * 132;
        const float4* w2v = (const float4*)W2;   // uniform -> s_load

        float M = 0.f, sj = 0.f, si = 0.f;
        #pragma unroll 8
        for (int h4 = 0; h4 < 32; ++h4) {
            float4 a = *(const float4*)(uj + h4 * 4);
            float4 c = *(const float4*)(ui + h4 * 4);
            float4 ww = w2v[h4];
            M  = fmaf(ww.x, fmaxf(a.x, c.x), M); sj = fmaf(ww.x, a.x, sj); si = fmaf(ww.x, c.x, si);
            M  = fmaf(ww.y, fmaxf(a.y, c.y), M); sj = fmaf(ww.y, a.y, sj); si = fmaf(ww.y, c.y, si);
            M  = fmaf(ww.z, fmaxf(a.z, c.z), M); sj = fmaf(ww.z, a.z, sj); si = fmaf(ww.z, c.z, si);
            M  = fmaf(ww.w, fmaxf(a.w, c.w), M); sj = fmaf(ww.w, a.w, sj); si = fmaf(ww.w, c.w, si);
        }
        const float Mw = (1.f - alpha) * M;
        outb[i * NJ + j] = Mw + alpha * sj - si;
        outb[j * NJ + i] = Mw + alpha * si - sj;
    } else if (t < 325) {
        const int i = t - 300;
        outb[i * (NJ + 1)] = 0.f;     // diagonal: d=0 -> prelu=0 exactly
    }
}

extern "C" void kernel_launch(void* const* d_in, const int* in_sizes, int n_in,
                              void* d_out, int out_size, void* d_ws, size_t ws_size,
                              hipStream_t stream) {
    // inputs: 0=src, 1=heads, 2=ends, 3=pair_ids (unused: telescoping), 4=W1, 5=alpha, 6=W2
    const float* src   = (const float*)d_in[0];
    const float* W1    = (const float*)d_in[4];
    const float* alpha = (const float*)d_in[5];
    const float* W2    = (const float*)d_in[6];
    float* out = (float*)d_out;

    const int B = in_sizes[0] / (NJ * CIN);   // 256
    fused_edge_mlp_v5<<<B, 512, 0, stream>>>(src, W1, alpha, W2, out);
}

// Round 6
// 73.760 us; speedup vs baseline: 1.0696x; 1.0696x over previous
//
#include <hip/hip_runtime.h>

// B=256, N=25, C=256, H/2=128.
// Telescoping: edge_feat[b,i,j,:] = src[b,j]-src[b,i]  =>  u = src @ W1^T (f16 MFMA).
// PReLU identity: max(d,0)=max(uj,ui)-ui =>
//   out[i,j] = (1-a)*M[i,j] + a*s_j - s_i,  M[i,j]=sum_h w2*max(uj,ui) (symmetric),
//   s_i = sum_h w2*u_i; diagonal exactly 0.  300 upper-tri pairs only.
//
// R6: R4's prep-kernel fragment pre-layout (proven best) + full f16 datapath:
//  - u kept in LDS as packed f16  -> phase-2 LDS b128 count halved
//  - v_pk_max_f16 + v_dot2_f32_f16 -> no unpack VALU in the pair loop
//  - s_i computed once per row by 25 side lanes (not per pair)
#define NJ   25
#define CIN  256
#define HH   128
#define US   136   // u16 row stride in shorts (272 B, 16B-aligned rows)

typedef _Float16 h2  __attribute__((ext_vector_type(2)));
typedef _Float16 h8f __attribute__((ext_vector_type(8)));
typedef __attribute__((ext_vector_type(4))) float f32x4;

__device__ __forceinline__ unsigned short f2h_bits(float f) {
    union { _Float16 h; unsigned short u; } v; v.h = (_Float16)f; return v.u;
}
__device__ __forceinline__ unsigned pack2h(float a, float b) {
    return (unsigned)f2h_bits(a) | ((unsigned)f2h_bits(b) << 16);
}
__device__ __forceinline__ h2 as_h2(unsigned u) {
    union { unsigned u; h2 h; } v; v.u = u; return v.h;
}

// ---------------- Kernel A: f16 fragment pre-layout -----------------------------
// srcfrag[gid*8]: f16 src[b][mt*16+(lane&15)][kt*32+(lane>>4)*8 ..+7], rows>=25 zero
// w1frag [id*8] : f16 W1[nt*16+(lane&15)][kt*32+(lane>>4)*8 ..+7]
// w2pk   [k]    : packed f16 {W2[2k], W2[2k+1]}
__global__ __launch_bounds__(256) void prep_frags(
    const float* __restrict__ src, const float* __restrict__ W1,
    const float* __restrict__ W2,
    unsigned short* __restrict__ srcfrag, unsigned short* __restrict__ w1frag,
    unsigned* __restrict__ w2pk, int nsrc)
{
    const int gid = blockIdx.x * 256 + threadIdx.x;
    const float* base;
    unsigned short* dst;
    if (gid < nsrc) {
        const int lane = gid & 63, kt = (gid >> 6) & 7, mt = (gid >> 9) & 1, b = gid >> 10;
        const int row = mt * 16 + (lane & 15);
        const int k0  = kt * 32 + (lane >> 4) * 8;
        dst = srcfrag + (size_t)gid * 8;
        if (row >= NJ) { *(uint4*)dst = make_uint4(0u, 0u, 0u, 0u); return; }
        base = src + ((size_t)b * NJ + row) * CIN + k0;
    } else if (gid < nsrc + 4096) {
        const int id = gid - nsrc;
        const int lane = id & 63, kt = (id >> 6) & 7, nt = id >> 9;
        const int row = nt * 16 + (lane & 15);
        const int k0  = kt * 32 + (lane >> 4) * 8;
        dst = w1frag + (size_t)id * 8;
        base = W1 + (size_t)row * CIN + k0;
    } else {
        const int id = gid - nsrc - 4096;
        if (id < HH / 2) w2pk[id] = pack2h(W2[2 * id], W2[2 * id + 1]);
        return;
    }
    float4 x = *(const float4*)base;
    float4 y = *(const float4*)(base + 4);
    uint4 o;
    o.x = pack2h(x.x, x.y); o.y = pack2h(x.z, x.w);
    o.z = pack2h(y.x, y.y); o.w = pack2h(y.z, y.w);
    *(uint4*)dst = o;
}

// ---------------- Kernel B: MFMA u-GEMM + f16 pair epilogue ---------------------
__global__ __launch_bounds__(512) void fused_edge_mlp_v6(
    const unsigned short* __restrict__ srcfrag,
    const unsigned short* __restrict__ w1frag,
    const unsigned* __restrict__ w2pk,   // 64 packed-f16 dwords
    const float* __restrict__ Aarr,      // [1] alpha
    float* __restrict__ out)             // [B,25,25]
{
    __shared__ unsigned short u16[NJ * US];   // u as f16, 6.8 KB
    __shared__ float s_s[NJ];                 // s_i = sum_h w2*u_i

    const int b    = blockIdx.x;
    const int t    = threadIdx.x;
    const int w    = t >> 6;
    const int lane = t & 63;
    const int ln15 = lane & 15;
    const int quad = lane >> 4;
    const int hcol = w * 16 + ln15;

    // ---- Phase 1: u = src_f16 @ W1_f16^T (pre-laid frags, contiguous wave loads)
    {
        const h8f* w1p = (const h8f*)w1frag + (w * 8) * 64 + lane;
        const h8f* ap  = (const h8f*)srcfrag + ((size_t)b * 16) * 64 + lane;

        h8f bfrag[8];
        #pragma unroll
        for (int kt = 0; kt < 8; ++kt) bfrag[kt] = w1p[kt * 64];

        f32x4 acc0 = {0.f, 0.f, 0.f, 0.f};
        f32x4 acc1 = {0.f, 0.f, 0.f, 0.f};
        #pragma unroll
        for (int kt = 0; kt < 8; ++kt) {
            acc0 = __builtin_amdgcn_mfma_f32_16x16x32_f16(ap[kt * 64],       bfrag[kt], acc0, 0, 0, 0);
            acc1 = __builtin_amdgcn_mfma_f32_16x16x32_f16(ap[(8 + kt) * 64], bfrag[kt], acc1, 0, 0, 0);
        }

        // D layout: col(h)=lane&15, row(m)=quad*4+reg
        #pragma unroll
        for (int r = 0; r < 4; ++r) {
            int m0 = quad * 4 + r;
            if (m0 < NJ) u16[m0 * US + hcol] = f2h_bits(acc0[r]);
            int m1 = 16 + quad * 4 + r;
            if (m1 < NJ) u16[m1 * US + hcol] = f2h_bits(acc1[r]);
        }
    }
    __syncthreads();

    // ---- Phase 2a: pair lanes compute M; side lanes compute s_i ----
    const float alpha = Aarr[0];
    float* outb = out + (size_t)b * (NJ * NJ);
    const uint4* w2v = (const uint4*)w2pk;    // uniform -> scalar loads

    float M = 0.f;
    int i = 0, j = 0;
    if (t < 300) {
        i = (int)((49.0f - sqrtf(2401.0f - 8.0f * (float)t)) * 0.5f);
        {   // fp-safety clamp
            int Si = (49 * i - i * i) >> 1;
            if (t < Si) { --i; }
            else { int Sn = (49 * (i + 1) - (i + 1) * (i + 1)) >> 1; if (t >= Sn) ++i; }
        }
        const int S = (49 * i - i * i) >> 1;
        j = t - S + i + 1;

        const uint4* ujp = (const uint4*)(u16 + j * US);
        const uint4* uip = (const uint4*)(u16 + i * US);
        #pragma unroll
        for (int h8 = 0; h8 < 16; ++h8) {
            uint4 a = ujp[h8], c = uip[h8], ww = w2v[h8];
            h2 mx;
            mx = __builtin_elementwise_max(as_h2(a.x), as_h2(c.x));
            M  = __builtin_amdgcn_fdot2(mx, as_h2(ww.x), M, false);
            mx = __builtin_elementwise_max(as_h2(a.y), as_h2(c.y));
            M  = __builtin_amdgcn_fdot2(mx, as_h2(ww.y), M, false);
            mx = __builtin_elementwise_max(as_h2(a.z), as_h2(c.z));
            M  = __builtin_amdgcn_fdot2(mx, as_h2(ww.z), M, false);
            mx = __builtin_elementwise_max(as_h2(a.w), as_h2(c.w));
            M  = __builtin_amdgcn_fdot2(mx, as_h2(ww.w), M, false);
        }
    } else if (t < 300 + NJ) {
        const int r = t - 300;
        const uint4* up = (const uint4*)(u16 + r * US);
        float s = 0.f;
        #pragma unroll
        for (int h8 = 0; h8 < 16; ++h8) {
            uint4 a = up[h8], ww = w2v[h8];
            s = __builtin_amdgcn_fdot2(as_h2(a.x), as_h2(ww.x), s, false);
            s = __builtin_amdgcn_fdot2(as_h2(a.y), as_h2(ww.y), s, false);
            s = __builtin_amdgcn_fdot2(as_h2(a.z), as_h2(ww.z), s, false);
            s = __builtin_amdgcn_fdot2(as_h2(a.w), as_h2(ww.w), s, false);
        }
        s_s[r] = s;
    }
    __syncthreads();

    // ---- Phase 2b: combine and write ----
    if (t < 300) {
        const float sj = s_s[j], si = s_s[i];
        const float Mw = (1.f - alpha) * M;
        outb[i * NJ + j] = Mw + alpha * sj - si;
        outb[j * NJ + i] = Mw + alpha * si - sj;
    } else if (t >= 325 && t < 350) {
        const int r = t - 325;
        outb[r * (NJ + 1)] = 0.f;     // diagonal: d=0 -> prelu=0 exactly
    }
}

extern "C" void kernel_launch(void* const* d_in, const int* in_sizes, int n_in,
                              void* d_out, int out_size, void* d_ws, size_t ws_size,
                              hipStream_t stream) {
    // inputs: 0=src, 1=heads, 2=ends, 3=pair_ids (unused: telescoping), 4=W1, 5=alpha, 6=W2
    const float* src   = (const float*)d_in[0];
    const float* W1    = (const float*)d_in[4];
    const float* alpha = (const float*)d_in[5];
    const float* W2    = (const float*)d_in[6];
    float* out = (float*)d_out;

    const int B    = in_sizes[0] / (NJ * CIN);            // 256
    const int nsrc = B * 16 * 64;                          // 262144 src frag chunks
    unsigned short* srcfrag = (unsigned short*)d_ws;       // nsrc*16 B (~4.2 MB)
    unsigned short* w1frag  = srcfrag + (size_t)nsrc * 8;  // 4096*16 B (64 KB)
    unsigned*       w2pk    = (unsigned*)(w1frag + 4096 * 8); // 64 dwords

    const int totalA = nsrc + 4096 + HH / 2;
    prep_frags<<<(totalA + 255) / 256, 256, 0, stream>>>(src, W1, W2, srcfrag, w1frag, w2pk, nsrc);
    fused_edge_mlp_v6<<<B, 512, 0, stream>>>(srcfrag, w1frag, w2pk, alpha, out);
}

// Round 8
// 72.491 us; speedup vs baseline: 1.0883x; 1.0175x over previous
//
#include <hip/hip_runtime.h>

// B=256, N=25, C=256, H/2=128.
// Telescoping: edge_feat[b,i,j,:] = src[b,j]-src[b,i]  =>  u = src @ W1^T (f16 MFMA).
// PReLU identity: max(d,0)=max(uj,ui)-ui =>
//   out[i,j] = (1-a)*M[i,j] + a*s_j - s_i,  M[i,j]=sum_h w2*max(uj,ui) (symmetric),
//   s_i = sum_h w2*u_i; diagonal exactly 0.  300 upper-tri pairs only.
//
// R8 = R7 with the staging-stride bug fixed: s_lds row pitch must hold 256
// shorts (f16), so SS=264 shorts (R7 had 132 = fp32-count stride -> row overlap).
#define NJ   25
#define CIN  256
#define HH   128
#define SS   264   // src_lds row stride in SHORTS (528 B; 256 data + 8 pad)
#define US   136   // u16 row stride in shorts (272 B)

typedef _Float16 h2  __attribute__((ext_vector_type(2)));
typedef _Float16 h4  __attribute__((ext_vector_type(4)));
typedef _Float16 h8f __attribute__((ext_vector_type(8)));
typedef __attribute__((ext_vector_type(4))) float f32x4;

__device__ __forceinline__ unsigned short f2h_bits(float f) {
    union { _Float16 h; unsigned short u; } v; v.h = (_Float16)f; return v.u;
}
__device__ __forceinline__ unsigned pack2h(float a, float b) {
    return (unsigned)f2h_bits(a) | ((unsigned)f2h_bits(b) << 16);
}
__device__ __forceinline__ h2 as_h2(unsigned u) {
    union { unsigned u; h2 h; } v; v.u = u; return v.h;
}

// ---------------- Kernel A: W1/W2 f16 fragment pre-layout (tiny) ----------------
// w1frag[id*8]: f16 W1[nt*16+(lane&15)][kt*32+(lane>>4)*8 ..+7]
// w2pk  [k]   : packed f16 {W2[2k], W2[2k+1]}
__global__ __launch_bounds__(256) void prep_w(
    const float* __restrict__ W1, const float* __restrict__ W2,
    unsigned short* __restrict__ w1frag, unsigned* __restrict__ w2pk)
{
    const int gid = blockIdx.x * 256 + threadIdx.x;
    if (gid < 4096) {
        const int lane = gid & 63, kt = (gid >> 6) & 7, nt = gid >> 9;
        const int row = nt * 16 + (lane & 15);
        const int k0  = kt * 32 + (lane >> 4) * 8;
        const float* base = W1 + (size_t)row * CIN + k0;
        float4 x = *(const float4*)base;
        float4 y = *(const float4*)(base + 4);
        uint4 o;
        o.x = pack2h(x.x, x.y); o.y = pack2h(x.z, x.w);
        o.z = pack2h(y.x, y.y); o.w = pack2h(y.z, y.w);
        *(uint4*)(w1frag + (size_t)gid * 8) = o;
    } else if (gid < 4096 + HH / 2) {
        const int id = gid - 4096;
        w2pk[id] = pack2h(W2[2 * id], W2[2 * id + 1]);
    }
}

// ---------------- Kernel B: src->LDS f16, MFMA u-GEMM, pair epilogue ------------
__global__ __launch_bounds__(512) void fused_edge_mlp_v8(
    const float* __restrict__ src,        // [B,25,256]
    const unsigned short* __restrict__ w1frag,
    const unsigned* __restrict__ w2pk,    // 64 packed-f16 dwords
    const float* __restrict__ Aarr,       // [1] alpha
    float* __restrict__ out)              // [B,25,25]
{
    __shared__ unsigned short s_lds[NJ * SS];   // src[b] as f16 (13.2 KB)
    __shared__ unsigned short u16[NJ * US];     // u as f16 (6.8 KB)
    __shared__ float s_s[NJ];                   // s_i

    const int b    = blockIdx.x;
    const int t    = threadIdx.x;
    const int w    = t >> 6;
    const int lane = t & 63;
    const int ln15 = lane & 15;
    const int quad = lane >> 4;
    const int hcol = w * 16 + ln15;

    // ---- Phase 0: coalesced src[b] -> LDS f16 (row-major, stride SS shorts) ----
    {
        const float4* s4 = (const float4*)(src + (size_t)b * NJ * CIN);
        for (int idx = t; idx < NJ * CIN / 4; idx += 512) {
            const int n = idx >> 6, k4 = idx & 63;
            float4 v = s4[idx];
            uint2 o = make_uint2(pack2h(v.x, v.y), pack2h(v.z, v.w));
            *(uint2*)&s_lds[n * SS + k4 * 4] = o;
        }
    }
    __syncthreads();

    // ---- Phase 1: u = src_f16 @ W1_f16^T (A from LDS, B pre-laid global) ----
    {
        const h8f* w1p = (const h8f*)w1frag + (w * 8) * 64 + lane;
        h8f bfrag[8];
        #pragma unroll
        for (int kt = 0; kt < 8; ++kt) bfrag[kt] = w1p[kt * 64];

        const int r1   = 16 + ln15;
        const bool r1ok = (r1 < NJ);
        const int cbase = quad * 8;

        f32x4 acc0 = {0.f, 0.f, 0.f, 0.f};
        f32x4 acc1 = {0.f, 0.f, 0.f, 0.f};
        #pragma unroll
        for (int kt = 0; kt < 8; ++kt) {
            const int co = kt * 32 + cbase;
            h4 lo0 = *(const h4*)&s_lds[ln15 * SS + co];
            h4 hi0 = *(const h4*)&s_lds[ln15 * SS + co + 4];
            h8f a0;
            a0[0] = lo0[0]; a0[1] = lo0[1]; a0[2] = lo0[2]; a0[3] = lo0[3];
            a0[4] = hi0[0]; a0[5] = hi0[1]; a0[6] = hi0[2]; a0[7] = hi0[3];
            h8f a1 = {};
            if (r1ok) {
                h4 lo1 = *(const h4*)&s_lds[r1 * SS + co];
                h4 hi1 = *(const h4*)&s_lds[r1 * SS + co + 4];
                a1[0] = lo1[0]; a1[1] = lo1[1]; a1[2] = lo1[2]; a1[3] = lo1[3];
                a1[4] = hi1[0]; a1[5] = hi1[1]; a1[6] = hi1[2]; a1[7] = hi1[3];
            }
            acc0 = __builtin_amdgcn_mfma_f32_16x16x32_f16(a0, bfrag[kt], acc0, 0, 0, 0);
            acc1 = __builtin_amdgcn_mfma_f32_16x16x32_f16(a1, bfrag[kt], acc1, 0, 0, 0);
        }

        // D layout: col(h)=lane&15, row(m)=quad*4+reg
        #pragma unroll
        for (int r = 0; r < 4; ++r) {
            int m0 = quad * 4 + r;
            if (m0 < NJ) u16[m0 * US + hcol] = f2h_bits(acc0[r]);
            int m1 = 16 + quad * 4 + r;
            if (m1 < NJ) u16[m1 * US + hcol] = f2h_bits(acc1[r]);
        }
    }
    __syncthreads();

    // ---- Phase 2a: pair lanes compute M; side lanes compute s_i ----
    const float alpha = Aarr[0];
    float* outb = out + (size_t)b * (NJ * NJ);
    const uint4* w2v = (const uint4*)w2pk;    // uniform -> scalar loads

    float M = 0.f;
    int i = 0, j = 0;
    if (t < 300) {
        i = (int)((49.0f - sqrtf(2401.0f - 8.0f * (float)t)) * 0.5f);
        {   // fp-safety clamp
            int Si = (49 * i - i * i) >> 1;
            if (t < Si) { --i; }
            else { int Sn = (49 * (i + 1) - (i + 1) * (i + 1)) >> 1; if (t >= Sn) ++i; }
        }
        const int S = (49 * i - i * i) >> 1;
        j = t - S + i + 1;

        const uint4* ujp = (const uint4*)(u16 + j * US);
        const uint4* uip = (const uint4*)(u16 + i * US);
        #pragma unroll
        for (int h8 = 0; h8 < 16; ++h8) {
            uint4 a = ujp[h8], c = uip[h8], ww = w2v[h8];
            h2 mx;
            mx = __builtin_elementwise_max(as_h2(a.x), as_h2(c.x));
            M  = __builtin_amdgcn_fdot2(mx, as_h2(ww.x), M, false);
            mx = __builtin_elementwise_max(as_h2(a.y), as_h2(c.y));
            M  = __builtin_amdgcn_fdot2(mx, as_h2(ww.y), M, false);
            mx = __builtin_elementwise_max(as_h2(a.z), as_h2(c.z));
            M  = __builtin_amdgcn_fdot2(mx, as_h2(ww.z), M, false);
            mx = __builtin_elementwise_max(as_h2(a.w), as_h2(c.w));
            M  = __builtin_amdgcn_fdot2(mx, as_h2(ww.w), M, false);
        }
    } else if (t < 300 + NJ) {
        const int r = t - 300;
        const uint4* up = (const uint4*)(u16 + r * US);
        float s = 0.f;
        #pragma unroll
        for (int h8 = 0; h8 < 16; ++h8) {
            uint4 a = up[h8], ww = w2v[h8];
            s = __builtin_amdgcn_fdot2(as_h2(a.x), as_h2(ww.x), s, false);
            s = __builtin_amdgcn_fdot2(as_h2(a.y), as_h2(ww.y), s, false);
            s = __builtin_amdgcn_fdot2(as_h2(a.z), as_h2(ww.z), s, false);
            s = __builtin_amdgcn_fdot2(as_h2(a.w), as_h2(ww.w), s, false);
        }
        s_s[r] = s;
    }
    __syncthreads();

    // ---- Phase 2b: combine and write ----
    if (t < 300) {
        const float sj = s_s[j], si = s_s[i];
        const float Mw = (1.f - alpha) * M;
        outb[i * NJ + j] = Mw + alpha * sj - si;
        outb[j * NJ + i] = Mw + alpha * si - sj;
    } else if (t >= 325 && t < 350) {
        const int r = t - 325;
        outb[r * (NJ + 1)] = 0.f;     // diagonal: d=0 -> prelu=0 exactly
    }
}

extern "C" void kernel_launch(void* const* d_in, const int* in_sizes, int n_in,
                              void* d_out, int out_size, void* d_ws, size_t ws_size,
                              hipStream_t stream) {
    // inputs: 0=src, 1=heads, 2=ends, 3=pair_ids (unused: telescoping), 4=W1, 5=alpha, 6=W2
    const float* src   = (const float*)d_in[0];
    const float* W1    = (const float*)d_in[4];
    const float* alpha = (const float*)d_in[5];
    const float* W2    = (const float*)d_in[6];
    float* out = (float*)d_out;

    const int B = in_sizes[0] / (NJ * CIN);               // 256
    unsigned short* w1frag = (unsigned short*)d_ws;       // 4096*16 B (64 KB)
    unsigned*       w2pk   = (unsigned*)(w1frag + 4096 * 8); // 64 dwords

    prep_w<<<17, 256, 0, stream>>>(W1, W2, w1frag, w2pk);
    fused_edge_mlp_v8<<<B, 512, 0, stream>>>(src, w1frag, w2pk, alpha, out);
}

// Round 9
// 72.122 us; speedup vs baseline: 1.0939x; 1.0051x over previous
//
#include <hip/hip_runtime.h>

// B=256, N=25, C=256, H/2=128.
// Telescoping: edge_feat[b,i,j,:] = src[b,j]-src[b,i]  =>  u = src @ W1^T (f16 MFMA).
// PReLU identity: max(d,0)=max(uj,ui)-ui =>
//   out[i,j] = (1-a)*M[i,j] + a*s_j - s_i,  M[i,j]=sum_h w2*max(uj,ui) (symmetric),
//   s_i = sum_h w2*u_i; diagonal exactly 0.  300 upper-tri pairs only.
//
// R9: SINGLE kernel / single graph node. W1 (128 KB fp32) is staged coalesced
// -> LDS f16 per block (like src), so no prep kernel, no ws round-trip, no
// inter-node dependency. All MFMA fragments (A and B) read as aligned
// ds_read_b128 from 264-short-stride LDS rows. W2 packed to LDS dwords in
// phase 0. LDS total ~88 KB, grid 256 = 1 block/CU.
#define NJ   25
#define CIN  256
#define HH   128
#define SS   264   // LDS row stride in SHORTS for src and W1 (528 B, 16B-aligned)
#define US   136   // u16 row stride in shorts (272 B)

typedef _Float16 h2  __attribute__((ext_vector_type(2)));
typedef _Float16 h8f __attribute__((ext_vector_type(8)));
typedef __attribute__((ext_vector_type(4))) float f32x4;

__device__ __forceinline__ unsigned short f2h_bits(float f) {
    union { _Float16 h; unsigned short u; } v; v.h = (_Float16)f; return v.u;
}
__device__ __forceinline__ unsigned pack2h(float a, float b) {
    return (unsigned)f2h_bits(a) | ((unsigned)f2h_bits(b) << 16);
}
__device__ __forceinline__ h2 as_h2(unsigned u) {
    union { unsigned u; h2 h; } v; v.u = u; return v.h;
}

__global__ __launch_bounds__(512) void fused_edge_mlp_v9(
    const float* __restrict__ src,   // [B,25,256]
    const float* __restrict__ W1,    // [128,256]
    const float* __restrict__ Aarr,  // [1] alpha
    const float* __restrict__ W2,    // [128]
    float* __restrict__ out)         // [B,25,25]
{
    __shared__ unsigned short w1_lds[HH * SS];  // W1 as f16 (67.6 KB)
    __shared__ unsigned short s_lds[NJ * SS];   // src[b] as f16 (13.2 KB)
    __shared__ unsigned short u16[NJ * US];     // u as f16 (6.8 KB)
    __shared__ unsigned w2s[HH / 2];            // packed f16 W2 (256 B)
    __shared__ float s_s[NJ];                   // s_i

    const int b    = blockIdx.x;
    const int t    = threadIdx.x;
    const int w    = t >> 6;
    const int lane = t & 63;
    const int ln15 = lane & 15;
    const int quad = lane >> 4;
    const int hcol = w * 16 + ln15;

    // ---- Phase 0: coalesced staging, fp32 -> f16 into LDS ----
    {
        // W1: 128 rows x 64 float4 = 8192 chunks (16/thread)
        const float4* w4 = (const float4*)W1;
        #pragma unroll 4
        for (int idx = t; idx < HH * CIN / 4; idx += 512) {
            const int r = idx >> 6, k4 = idx & 63;
            float4 v = w4[idx];
            *(uint2*)&w1_lds[r * SS + k4 * 4] =
                make_uint2(pack2h(v.x, v.y), pack2h(v.z, v.w));
        }
        // src[b]: 25 rows x 64 float4 = 1600 chunks
        const float4* s4 = (const float4*)(src + (size_t)b * NJ * CIN);
        for (int idx = t; idx < NJ * CIN / 4; idx += 512) {
            const int n = idx >> 6, k4 = idx & 63;
            float4 v = s4[idx];
            *(uint2*)&s_lds[n * SS + k4 * 4] =
                make_uint2(pack2h(v.x, v.y), pack2h(v.z, v.w));
        }
        // W2: 64 packed dwords
        if (t < HH / 2) w2s[t] = pack2h(W2[2 * t], W2[2 * t + 1]);
    }
    __syncthreads();

    // ---- Phase 1: u = src_f16 @ W1_f16^T, all fragments as aligned b128 ----
    {
        const int r1    = 16 + ln15;
        const bool r1ok = (r1 < NJ);
        const int cbase = quad * 8;

        f32x4 acc0 = {0.f, 0.f, 0.f, 0.f};
        f32x4 acc1 = {0.f, 0.f, 0.f, 0.f};
        #pragma unroll
        for (int kt = 0; kt < 8; ++kt) {
            const int co = kt * 32 + cbase;
            h8f bf = *(const h8f*)&w1_lds[hcol * SS + co];
            h8f a0 = *(const h8f*)&s_lds[ln15 * SS + co];
            h8f a1 = {};
            if (r1ok) a1 = *(const h8f*)&s_lds[r1 * SS + co];
            acc0 = __builtin_amdgcn_mfma_f32_16x16x32_f16(a0, bf, acc0, 0, 0, 0);
            acc1 = __builtin_amdgcn_mfma_f32_16x16x32_f16(a1, bf, acc1, 0, 0, 0);
        }

        // D layout: col(h)=lane&15, row(m)=quad*4+reg
        #pragma unroll
        for (int r = 0; r < 4; ++r) {
            int m0 = quad * 4 + r;
            if (m0 < NJ) u16[m0 * US + hcol] = f2h_bits(acc0[r]);
            int m1 = 16 + quad * 4 + r;
            if (m1 < NJ) u16[m1 * US + hcol] = f2h_bits(acc1[r]);
        }
    }
    __syncthreads();

    // ---- Phase 2a: pair lanes compute M; side lanes compute s_i ----
    const float alpha = Aarr[0];
    float* outb = out + (size_t)b * (NJ * NJ);
    const uint4* w2v = (const uint4*)w2s;   // uniform -> LDS broadcast

    float M = 0.f;
    int i = 0, j = 0;
    if (t < 300) {
        i = (int)((49.0f - sqrtf(2401.0f - 8.0f * (float)t)) * 0.5f);
        {   // fp-safety clamp
            int Si = (49 * i - i * i) >> 1;
            if (t < Si) { --i; }
            else { int Sn = (49 * (i + 1) - (i + 1) * (i + 1)) >> 1; if (t >= Sn) ++i; }
        }
        const int S = (49 * i - i * i) >> 1;
        j = t - S + i + 1;

        const uint4* ujp = (const uint4*)(u16 + j * US);
        const uint4* uip = (const uint4*)(u16 + i * US);
        #pragma unroll
        for (int h8 = 0; h8 < 16; ++h8) {
            uint4 a = ujp[h8], c = uip[h8], ww = w2v[h8];
            h2 mx;
            mx = __builtin_elementwise_max(as_h2(a.x), as_h2(c.x));
            M  = __builtin_amdgcn_fdot2(mx, as_h2(ww.x), M, false);
            mx = __builtin_elementwise_max(as_h2(a.y), as_h2(c.y));
            M  = __builtin_amdgcn_fdot2(mx, as_h2(ww.y), M, false);
            mx = __builtin_elementwise_max(as_h2(a.z), as_h2(c.z));
            M  = __builtin_amdgcn_fdot2(mx, as_h2(ww.z), M, false);
            mx = __builtin_elementwise_max(as_h2(a.w), as_h2(c.w));
            M  = __builtin_amdgcn_fdot2(mx, as_h2(ww.w), M, false);
        }
    } else if (t < 300 + NJ) {
        const int r = t - 300;
        const uint4* up = (const uint4*)(u16 + r * US);
        float s = 0.f;
        #pragma unroll
        for (int h8 = 0; h8 < 16; ++h8) {
            uint4 a = up[h8], ww = w2v[h8];
            s = __builtin_amdgcn_fdot2(as_h2(a.x), as_h2(ww.x), s, false);
            s = __builtin_amdgcn_fdot2(as_h2(a.y), as_h2(ww.y), s, false);
            s = __builtin_amdgcn_fdot2(as_h2(a.z), as_h2(ww.z), s, false);
            s = __builtin_amdgcn_fdot2(as_h2(a.w), as_h2(ww.w), s, false);
        }
        s_s[r] = s;
    }
    __syncthreads();

    // ---- Phase 2b: combine and write ----
    if (t < 300) {
        const float sj = s_s[j], si = s_s[i];
        const float Mw = (1.f - alpha) * M;
        outb[i * NJ + j] = Mw + alpha * sj - si;
        outb[j * NJ + i] = Mw + alpha * si - sj;
    } else if (t >= 325 && t < 350) {
        const int r = t - 325;
        outb[r * (NJ + 1)] = 0.f;     // diagonal: d=0 -> prelu=0 exactly
    }
}

extern "C" void kernel_launch(void* const* d_in, const int* in_sizes, int n_in,
                              void* d_out, int out_size, void* d_ws, size_t ws_size,
                              hipStream_t stream) {
    // inputs: 0=src, 1=heads, 2=ends, 3=pair_ids (unused: telescoping), 4=W1, 5=alpha, 6=W2
    const float* src   = (const float*)d_in[0];
    const float* W1    = (const float*)d_in[4];
    const float* alpha = (const float*)d_in[5];
    const float* W2    = (const float*)d_in[6];
    float* out = (float*)d_out;

    const int B = in_sizes[0] / (NJ * CIN);   // 256
    fused_edge_mlp_v9<<<B, 512, 0, stream>>>(src, W1, alpha, W2, out);
}